// Round 1
// baseline (356.173 us; speedup 1.0000x reference)
//
#include <hip/hip_runtime.h>

// CandidateScorer on MI355X (gfx950).
//
// Restructured math (exact rewrite of the reference):
//   gp-part of combined is candidate-independent      -> folded into bias b1'
//   go/to gathers take only 361 distinct values each  -> precomputed tables
//        T_go[pos,j] = sum_c pfm[c,pos] * W1[c,       j-slice 0:256]
//        T_to[pos,j] = sum_c pfm[c,pos] * W1[256+c,   ...]
//   h1[n,j] = relu(T_go[go[n],j] + T_to[to[n],j] + (cand @ W1c)[n,j] + b1'[j])
//   scores  = relu(h1 @ W2 + b2) @ W3 + b3   (GEMM3 fused into GEMM2 epilogue)
//
// Heavy kernels are bf16 MFMA GEMMs (m97-style: 128x128 tile, BK=32,
// global_load_lds width=16, B^T layout for ds_read_b128 fragments).

using bf16x8 = __attribute__((ext_vector_type(8))) __bf16;
using f32x4  = __attribute__((ext_vector_type(4))) float;

__device__ __forceinline__ unsigned short f2bf(float f) {
  unsigned int u = __float_as_uint(f);
  u += 0x7fffu + ((u >> 16) & 1u);          // round-to-nearest-even
  return (unsigned short)(u >> 16);
}

// Async global->LDS, 16B per lane. LDS dest is wave-uniform base + lane*16.
__device__ __forceinline__ void async_copy16(const void* g, void* l) {
  __builtin_amdgcn_global_load_lds(
      (__attribute__((address_space(1))) void*)(unsigned long long)g,
      (__attribute__((address_space(3))) void*)(unsigned int)(unsigned long long)l,
      16, 0, 0);
}

// ---------------------------------------------------------------- prep kernels

// gp[c] = mean over 19x19 of pfm[c]. one wave per channel.
__global__ void pool_kernel(const float* __restrict__ pfm, float* __restrict__ gp) {
  int c = blockIdx.x;
  int lane = threadIdx.x;
  float s = 0.f;
  for (int i = lane; i < 361; i += 64) s += pfm[c * 361 + i];
#pragma unroll
  for (int off = 32; off > 0; off >>= 1) s += __shfl_down(s, off, 64);
  if (lane == 0) gp[c] = s * (1.0f / 361.0f);
}

// b1p[j] = b1[j] + sum_c gp[c] * W1[512+c][j]
__global__ void b1p_kernel(const float* __restrict__ W1, const float* __restrict__ b1,
                           const float* __restrict__ gp, float* __restrict__ b1p) {
  __shared__ float g[256];
  int t = threadIdx.x;
  g[t] = gp[t];
  __syncthreads();
  int j = blockIdx.x * 256 + t;
  float acc = b1[j];
  for (int c = 0; c < 256; c++) acc += g[c] * W1[(size_t)(512 + c) * 1024 + j];
  b1p[j] = acc;
}

// T[s][pos][j] = sum_c pfm[c][pos] * W1[s*256+c][j]; 4 positions per block
// so the coalesced W1 read is reused 4x.
__global__ void ttab_kernel(const float* __restrict__ pfm, const float* __restrict__ W1,
                            float* __restrict__ T) {
  int bx = blockIdx.x;              // 2 * 91 * 4 = 728 blocks
  int s = bx / 364;
  int rem = bx % 364;
  int p4 = rem >> 2;
  int jc = rem & 3;
  int t = threadIdx.x;
  int j = jc * 256 + t;
  __shared__ float pf[4][256];
#pragma unroll
  for (int i = 0; i < 4; i++) {
    int p = p4 * 4 + i;
    pf[i][t] = (p < 361) ? pfm[t * 361 + p] : 0.f;   // t = channel
  }
  __syncthreads();
  float a0 = 0.f, a1 = 0.f, a2 = 0.f, a3 = 0.f;
  for (int c = 0; c < 256; c++) {
    float w = W1[(size_t)(s * 256 + c) * 1024 + j];
    a0 += pf[0][c] * w; a1 += pf[1][c] * w; a2 += pf[2][c] * w; a3 += pf[3][c] * w;
  }
  float acc[4] = {a0, a1, a2, a3};
#pragma unroll
  for (int i = 0; i < 4; i++) {
    int p = p4 * 4 + i;
    if (p < 361) T[((size_t)s * 361 + p) * 1024 + j] = acc[i];
  }
}

// go/to flat board offsets, identical fp32 arithmetic to the reference.
__global__ void decode_kernel(const float* __restrict__ cand, int* __restrict__ go_off,
                              int* __restrict__ to_off) {
  int n = blockIdx.x * 256 + threadIdx.x;
  const float* cf = cand + (size_t)n * 64;
  int gr = min(max((int)(cf[5] * 18.0f), 0), 18);
  int gc = min(max((int)(cf[6] * 18.0f), 0), 18);
  int tr = min(max((int)(cf[7] * 18.0f), 0), 18);
  int tc = min(max((int)(cf[8] * 18.0f), 0), 18);
  go_off[n] = gr * 19 + gc;
  to_off[n] = tr * 19 + tc;
}

// flat f32 -> bf16 (cand_feats)
__global__ void cvt_bf16_kernel(const float* __restrict__ in, unsigned short* __restrict__ out) {
  int i = blockIdx.x * 256 + threadIdx.x;
  out[i] = f2bf(in[i]);
}

// w1cT[n][k] = bf16(W1[768+k][n]),  n<1024, k<64
__global__ void w1ct_kernel(const float* __restrict__ W1, unsigned short* __restrict__ w1cT) {
  int o = blockIdx.x * 256 + threadIdx.x;  // < 65536
  int n = o >> 6, k = o & 63;
  w1cT[o] = f2bf(W1[(size_t)(768 + k) * 1024 + n]);
}

// w2T[n][k] = bf16(W2[k][n]),  1024x1024
__global__ void w2t_kernel(const float* __restrict__ W2, unsigned short* __restrict__ w2T) {
  int o = blockIdx.x * 256 + threadIdx.x;  // < 1048576
  int n = o >> 10, k = o & 1023;
  w2T[o] = f2bf(W2[(size_t)k * 1024 + n]);
}

// scores[i] = b3 (atomic accumulation target for the fused GEMM2/GEMM3)
__global__ void init_scores_kernel(float* __restrict__ scores, const float* __restrict__ b3) {
  int i = blockIdx.x * 256 + threadIdx.x;
  scores[i] = b3[0];
}

// ---------------------------------------------------------------- GEMM (BT)

// C(M x 1024) = A(M x K, bf16, row-major) * BT(1024 x K, bf16, row-major)^T
// 128x128 tile per 256-thread block, BK=32, wave w=(wm,wn) owns a 64x64
// subtile as 4x4 mfma_f32_16x16x32_bf16 accumulators.
// EPI==0: h1 epilogue  (+T_go gather, +T_to gather, +bias, relu, bf16 store)
// EPI==1: score epilogue (relu(x+b2) dot w3, shfl-reduce over 16 cols, atomicAdd)
template <int EPI>
__launch_bounds__(256, 2)
__global__ void gemm_bt(const unsigned short* __restrict__ A,
                        const unsigned short* __restrict__ BT,
                        int K,
                        unsigned short* __restrict__ h1out,
                        const float* __restrict__ Ttab,
                        const int* __restrict__ go_off,
                        const int* __restrict__ to_off,
                        const float* __restrict__ bias,
                        const float* __restrict__ w3,
                        float* __restrict__ scores) {
  __shared__ unsigned short As[128 * 32];  // [row][k] 8KB
  __shared__ unsigned short Bs[128 * 32];  // [n][k]   8KB

  const int tid  = threadIdx.x;
  const int lane = tid & 63;
  const int wave = tid >> 6;
  const int wm   = wave & 1;
  const int wn   = wave >> 1;
  const int quad = lane >> 4;
  const int r16  = lane & 15;

  const int bx    = blockIdx.x;
  const long rowbase = (long)(bx >> 3) * 128;
  const int  colbase = (bx & 7) * 128;

  const f32x4 zero4 = {0.f, 0.f, 0.f, 0.f};
  f32x4 acc[4][4];
#pragma unroll
  for (int i = 0; i < 4; i++)
#pragma unroll
    for (int j = 0; j < 4; j++) acc[i][j] = zero4;

  // staging: 512 chunks of 16B per tile; thread owns chunks tid and tid+256.
  // chunk c -> row = c>>2, colchunk = c&3; LDS offset = c*16B (wave-contiguous).
  const int row0 = tid >> 2, cc0 = tid & 3;
  const int row1 = (tid + 256) >> 2, cc1 = (tid + 256) & 3;
  unsigned short* lA0 = &As[(wave * 64) * 8];          // wave-uniform bases
  unsigned short* lA1 = &As[(256 + wave * 64) * 8];
  unsigned short* lB0 = &Bs[(wave * 64) * 8];
  unsigned short* lB1 = &Bs[(256 + wave * 64) * 8];
  const unsigned short* gA0 = A + (rowbase + row0) * K + cc0 * 8;
  const unsigned short* gA1 = A + (rowbase + row1) * K + cc1 * 8;
  const unsigned short* gB0 = BT + (long)(colbase + row0) * K + cc0 * 8;
  const unsigned short* gB1 = BT + (long)(colbase + row1) * K + cc1 * 8;

  for (int k0 = 0; k0 < K; k0 += 32) {
    async_copy16(gA0 + k0, lA0);
    async_copy16(gA1 + k0, lA1);
    async_copy16(gB0 + k0, lB0);
    async_copy16(gB1 + k0, lB1);
    __syncthreads();  // compiler drains vmcnt before s_barrier -> LDS ready

    bf16x8 af[4], bfv[4];
#pragma unroll
    for (int mi = 0; mi < 4; mi++)
      af[mi] = *(const bf16x8*)&As[(wm * 64 + mi * 16 + r16) * 32 + quad * 8];
#pragma unroll
    for (int ni = 0; ni < 4; ni++)
      bfv[ni] = *(const bf16x8*)&Bs[(wn * 64 + ni * 16 + r16) * 32 + quad * 8];
#pragma unroll
    for (int mi = 0; mi < 4; mi++)
#pragma unroll
      for (int ni = 0; ni < 4; ni++)
        acc[mi][ni] = __builtin_amdgcn_mfma_f32_16x16x32_bf16(af[mi], bfv[ni],
                                                              acc[mi][ni], 0, 0, 0);
    __syncthreads();  // LDS reads done before next-tile staging overwrites
  }

  // C/D layout: col = lane&15, row = quad*4 + reg  (m89/m91-verified)
  if constexpr (EPI == 0) {
#pragma unroll
    for (int mi = 0; mi < 4; mi++) {
#pragma unroll
      for (int reg = 0; reg < 4; reg++) {
        long row = rowbase + wm * 64 + mi * 16 + quad * 4 + reg;
        const float* tg = Ttab + (long)go_off[row] * 1024;
        const float* tt = Ttab + (long)361 * 1024 + (long)to_off[row] * 1024;
#pragma unroll
        for (int ni = 0; ni < 4; ni++) {
          int col = colbase + wn * 64 + ni * 16 + r16;
          float v = acc[mi][ni][reg] + tg[col] + tt[col] + bias[col];
          h1out[row * 1024 + col] = f2bf(fmaxf(v, 0.f));
        }
      }
    }
  } else {
#pragma unroll
    for (int mi = 0; mi < 4; mi++) {
#pragma unroll
      for (int reg = 0; reg < 4; reg++) {
        long row = rowbase + wm * 64 + mi * 16 + quad * 4 + reg;
        float part = 0.f;
#pragma unroll
        for (int ni = 0; ni < 4; ni++) {
          int col = colbase + wn * 64 + ni * 16 + r16;
          float v = fmaxf(acc[mi][ni][reg] + bias[col], 0.f);
          part += v * w3[col];
        }
        part += __shfl_xor(part, 1, 16);
        part += __shfl_xor(part, 2, 16);
        part += __shfl_xor(part, 4, 16);
        part += __shfl_xor(part, 8, 16);
        if (r16 == 0) atomicAdd(&scores[row], part);
      }
    }
  }
}

// ---------------------------------------------------------------- launch

extern "C" void kernel_launch(void* const* d_in, const int* in_sizes, int n_in,
                              void* d_out, int out_size, void* d_ws, size_t ws_size,
                              hipStream_t stream) {
  const float* pfm  = (const float*)d_in[0];  // (256,19,19)
  const float* cand = (const float*)d_in[1];  // (65536,64)
  const float* W1   = (const float*)d_in[2];  // (832,1024)
  const float* b1   = (const float*)d_in[3];  // (1024,)
  const float* W2   = (const float*)d_in[4];  // (1024,1024)
  const float* b2   = (const float*)d_in[5];  // (1024,)
  const float* W3   = (const float*)d_in[6];  // (1024,1)
  const float* b3   = (const float*)d_in[7];  // (1,)
  float* scores = (float*)d_out;              // (65536,)

  char* ws = (char*)d_ws;
  float*          gp      = (float*)(ws + 0);          //   1 KB
  float*          b1p     = (float*)(ws + 1024);       //   4 KB
  float*          Ttab    = (float*)(ws + 8192);       // 2*361*1024*4 = 2.83 MB
  int*            go_off  = (int*)(ws + 2965504);      // 256 KB
  int*            to_off  = (int*)(ws + 3227648);      // 256 KB
  unsigned short* cand_bf = (unsigned short*)(ws + 3489792);   // 8 MB
  unsigned short* w1cT    = (unsigned short*)(ws + 11878400);  // 128 KB
  unsigned short* w2T     = (unsigned short*)(ws + 12009472);  // 2 MB
  unsigned short* h1      = (unsigned short*)(ws + 14106624);  // 128 MB
  // total ws need: 148,324,352 bytes
  if (ws_size < 148324352) return;  // loud correctness failure instead of corruption

  pool_kernel<<<256, 64, 0, stream>>>(pfm, gp);
  b1p_kernel<<<4, 256, 0, stream>>>(W1, b1, gp, b1p);
  ttab_kernel<<<728, 256, 0, stream>>>(pfm, W1, Ttab);
  decode_kernel<<<256, 256, 0, stream>>>(cand, go_off, to_off);
  cvt_bf16_kernel<<<16384, 256, 0, stream>>>(cand, cand_bf);   // 65536*64
  w1ct_kernel<<<256, 256, 0, stream>>>(W1, w1cT);
  w2t_kernel<<<4096, 256, 0, stream>>>(W2, w2T);
  init_scores_kernel<<<256, 256, 0, stream>>>(scores, b3);

  // h1 = relu(cand@W1c + T_go[g] + T_to[t] + b1')   M=65536,K=64
  gemm_bt<0><<<4096, 256, 0, stream>>>(cand_bf, w1cT, 64, h1, Ttab, go_off, to_off,
                                       b1p, nullptr, nullptr);
  // scores += relu(h1@W2 + b2) @ w3                 M=65536,K=1024
  gemm_bt<1><<<4096, 256, 0, stream>>>(h1, w2T, 1024, nullptr, nullptr, nullptr,
                                       nullptr, b2, W3, scores);
}

// Round 2
// 328.585 us; speedup vs baseline: 1.0840x; 1.0840x over previous
//
#include <hip/hip_runtime.h>

// CandidateScorer on MI355X (gfx950).
//
// Restructured math (exact rewrite of the reference):
//   gp-part of combined is candidate-independent      -> folded into bias b1'
//   go/to gathers take only 361 distinct values each  -> precomputed tables
//        T_go[pos,j] = sum_c pfm[c,pos] * W1[c,       j-slice 0:256]
//        T_to[pos,j] = sum_c pfm[c,pos] * W1[256+c,   ...]
//   h1[n,j] = relu(T_go[go[n],j] + T_to[to[n],j] + (cand @ W1c)[n,j] + b1'[j])
//   scores  = relu(h1 @ W2 + b2) @ W3 + b3   (GEMM3 fused into GEMM2 epilogue)
//
// R1: +XCD-aware swizzle (8 blocks sharing an A-tile -> same XCD's L2;
//     FETCH was 4x ideal), +LDS-staged coalesced h1 stores in GEMM1 epilogue.

using bf16x8 = __attribute__((ext_vector_type(8))) __bf16;
using f32x4  = __attribute__((ext_vector_type(4))) float;
using i32x4  = __attribute__((ext_vector_type(4))) int;

__device__ __forceinline__ unsigned short f2bf(float f) {
  unsigned int u = __float_as_uint(f);
  u += 0x7fffu + ((u >> 16) & 1u);          // round-to-nearest-even
  return (unsigned short)(u >> 16);
}

// Async global->LDS, 16B per lane. LDS dest is wave-uniform base + lane*16.
__device__ __forceinline__ void async_copy16(const void* g, void* l) {
  __builtin_amdgcn_global_load_lds(
      (__attribute__((address_space(1))) void*)(unsigned long long)g,
      (__attribute__((address_space(3))) void*)(unsigned int)(unsigned long long)l,
      16, 0, 0);
}

// ---------------------------------------------------------------- prep kernels

// gp[c] = mean over 19x19 of pfm[c]. one wave per channel.
__global__ void pool_kernel(const float* __restrict__ pfm, float* __restrict__ gp) {
  int c = blockIdx.x;
  int lane = threadIdx.x;
  float s = 0.f;
  for (int i = lane; i < 361; i += 64) s += pfm[c * 361 + i];
#pragma unroll
  for (int off = 32; off > 0; off >>= 1) s += __shfl_down(s, off, 64);
  if (lane == 0) gp[c] = s * (1.0f / 361.0f);
}

// b1p[j] = b1[j] + sum_c gp[c] * W1[512+c][j]
__global__ void b1p_kernel(const float* __restrict__ W1, const float* __restrict__ b1,
                           const float* __restrict__ gp, float* __restrict__ b1p) {
  __shared__ float g[256];
  int t = threadIdx.x;
  g[t] = gp[t];
  __syncthreads();
  int j = blockIdx.x * 256 + t;
  float acc = b1[j];
  for (int c = 0; c < 256; c++) acc += g[c] * W1[(size_t)(512 + c) * 1024 + j];
  b1p[j] = acc;
}

// T[s][pos][j] = sum_c pfm[c][pos] * W1[s*256+c][j]; 4 positions per block
// so the coalesced W1 read is reused 4x.
__global__ void ttab_kernel(const float* __restrict__ pfm, const float* __restrict__ W1,
                            float* __restrict__ T) {
  int bx = blockIdx.x;              // 2 * 91 * 4 = 728 blocks
  int s = bx / 364;
  int rem = bx % 364;
  int p4 = rem >> 2;
  int jc = rem & 3;
  int t = threadIdx.x;
  int j = jc * 256 + t;
  __shared__ float pf[4][256];
#pragma unroll
  for (int i = 0; i < 4; i++) {
    int p = p4 * 4 + i;
    pf[i][t] = (p < 361) ? pfm[t * 361 + p] : 0.f;   // t = channel
  }
  __syncthreads();
  float a0 = 0.f, a1 = 0.f, a2 = 0.f, a3 = 0.f;
  for (int c = 0; c < 256; c++) {
    float w = W1[(size_t)(s * 256 + c) * 1024 + j];
    a0 += pf[0][c] * w; a1 += pf[1][c] * w; a2 += pf[2][c] * w; a3 += pf[3][c] * w;
  }
  float acc[4] = {a0, a1, a2, a3};
#pragma unroll
  for (int i = 0; i < 4; i++) {
    int p = p4 * 4 + i;
    if (p < 361) T[((size_t)s * 361 + p) * 1024 + j] = acc[i];
  }
}

// go/to flat board offsets, identical fp32 arithmetic to the reference.
__global__ void decode_kernel(const float* __restrict__ cand, int* __restrict__ go_off,
                              int* __restrict__ to_off) {
  int n = blockIdx.x * 256 + threadIdx.x;
  const float* cf = cand + (size_t)n * 64;
  int gr = min(max((int)(cf[5] * 18.0f), 0), 18);
  int gc = min(max((int)(cf[6] * 18.0f), 0), 18);
  int tr = min(max((int)(cf[7] * 18.0f), 0), 18);
  int tc = min(max((int)(cf[8] * 18.0f), 0), 18);
  go_off[n] = gr * 19 + gc;
  to_off[n] = tr * 19 + tc;
}

// flat f32 -> bf16 (cand_feats)
__global__ void cvt_bf16_kernel(const float* __restrict__ in, unsigned short* __restrict__ out) {
  int i = blockIdx.x * 256 + threadIdx.x;
  out[i] = f2bf(in[i]);
}

// w1cT[n][k] = bf16(W1[768+k][n]),  n<1024, k<64
__global__ void w1ct_kernel(const float* __restrict__ W1, unsigned short* __restrict__ w1cT) {
  int o = blockIdx.x * 256 + threadIdx.x;  // < 65536
  int n = o >> 6, k = o & 63;
  w1cT[o] = f2bf(W1[(size_t)(768 + k) * 1024 + n]);
}

// w2T[n][k] = bf16(W2[k][n]),  1024x1024
__global__ void w2t_kernel(const float* __restrict__ W2, unsigned short* __restrict__ w2T) {
  int o = blockIdx.x * 256 + threadIdx.x;  // < 1048576
  int n = o >> 10, k = o & 1023;
  w2T[o] = f2bf(W2[(size_t)k * 1024 + n]);
}

// scores[i] = b3 (atomic accumulation target for the fused GEMM2/GEMM3)
__global__ void init_scores_kernel(float* __restrict__ scores, const float* __restrict__ b3) {
  int i = blockIdx.x * 256 + threadIdx.x;
  scores[i] = b3[0];
}

// ---------------------------------------------------------------- GEMM (BT)

// C(M x 1024) = A(M x K, bf16, row-major) * BT(1024 x K, bf16, row-major)^T
// 128x128 tile per 256-thread block, BK=32, wave w=(wm,wn) owns a 64x64
// subtile as 4x4 mfma_f32_16x16x32_bf16 accumulators.
// Block->tile mapping is XCD-aware: dispatch round-robins blocks across the
// 8 XCDs (bx%8), so we keep all 8 column-tiles of one row-tile on ONE XCD
// (consecutive on that XCD) -> the shared A-tile stays in its 4MB L2.
// EPI==0: h1 epilogue  (+T_go/+T_to gather, +bias, relu, bf16 store via
//         padded-LDS restage for 16B-coalesced global stores)
// EPI==1: score epilogue (relu(x+b2) dot w3, shfl-reduce over 16 cols, atomicAdd)
template <int EPI>
__launch_bounds__(256, 2)
__global__ void gemm_bt(const unsigned short* __restrict__ A,
                        const unsigned short* __restrict__ BT,
                        int K,
                        unsigned short* __restrict__ h1out,
                        const float* __restrict__ Ttab,
                        const int* __restrict__ go_off,
                        const int* __restrict__ to_off,
                        const float* __restrict__ bias,
                        const float* __restrict__ w3,
                        float* __restrict__ scores) {
  __shared__ unsigned short As[128 * 32];  // [row][k] 8KB
  __shared__ unsigned short Bs[128 * 32];  // [n][k]   8KB

  const int tid  = threadIdx.x;
  const int lane = tid & 63;
  const int wave = tid >> 6;
  const int wm   = wave & 1;
  const int wn   = wave >> 1;
  const int quad = lane >> 4;
  const int r16  = lane & 15;

  // XCD-aware swizzle: xcd = bx&7; per-XCD sequence index k = bx>>3;
  // 8 consecutive blocks on one XCD share mtile.
  const int bx    = blockIdx.x;
  const int xcd   = bx & 7;
  const int seq   = bx >> 3;
  const int ntile = seq & 7;
  const int mtile = ((seq >> 3) << 3) | xcd;
  const long rowbase = (long)mtile * 128;
  const int  colbase = ntile * 128;

  const f32x4 zero4 = {0.f, 0.f, 0.f, 0.f};
  f32x4 acc[4][4];
#pragma unroll
  for (int i = 0; i < 4; i++)
#pragma unroll
    for (int j = 0; j < 4; j++) acc[i][j] = zero4;

  // staging: 512 chunks of 16B per tile; thread owns chunks tid and tid+256.
  // chunk c -> row = c>>2, colchunk = c&3; LDS offset = c*16B (wave-contiguous).
  const int row0 = tid >> 2, cc0 = tid & 3;
  const int row1 = (tid + 256) >> 2, cc1 = (tid + 256) & 3;
  unsigned short* lA0 = &As[(wave * 64) * 8];          // wave-uniform bases
  unsigned short* lA1 = &As[(256 + wave * 64) * 8];
  unsigned short* lB0 = &Bs[(wave * 64) * 8];
  unsigned short* lB1 = &Bs[(256 + wave * 64) * 8];
  const unsigned short* gA0 = A + (rowbase + row0) * K + cc0 * 8;
  const unsigned short* gA1 = A + (rowbase + row1) * K + cc1 * 8;
  const unsigned short* gB0 = BT + (long)(colbase + row0) * K + cc0 * 8;
  const unsigned short* gB1 = BT + (long)(colbase + row1) * K + cc1 * 8;

  for (int k0 = 0; k0 < K; k0 += 32) {
    async_copy16(gA0 + k0, lA0);
    async_copy16(gA1 + k0, lA1);
    async_copy16(gB0 + k0, lB0);
    async_copy16(gB1 + k0, lB1);
    __syncthreads();  // compiler drains vmcnt before s_barrier -> LDS ready

    bf16x8 af[4], bfv[4];
#pragma unroll
    for (int mi = 0; mi < 4; mi++)
      af[mi] = *(const bf16x8*)&As[(wm * 64 + mi * 16 + r16) * 32 + quad * 8];
#pragma unroll
    for (int ni = 0; ni < 4; ni++)
      bfv[ni] = *(const bf16x8*)&Bs[(wn * 64 + ni * 16 + r16) * 32 + quad * 8];
#pragma unroll
    for (int mi = 0; mi < 4; mi++)
#pragma unroll
      for (int ni = 0; ni < 4; ni++)
        acc[mi][ni] = __builtin_amdgcn_mfma_f32_16x16x32_bf16(af[mi], bfv[ni],
                                                              acc[mi][ni], 0, 0, 0);
    __syncthreads();  // LDS reads done before next-tile staging overwrites
  }

  // C/D layout: col = lane&15, row = quad*4 + reg  (m89/m91-verified)
  if constexpr (EPI == 0) {
    // Stage the bf16 tile in LDS (row stride 136 shorts = 68 words: de-aliases
    // banks across rows for the read-back), then 16B-coalesced global stores.
    __shared__ unsigned short Cs[128 * 136];  // 34 KB
#pragma unroll
    for (int mi = 0; mi < 4; mi++) {
#pragma unroll
      for (int reg = 0; reg < 4; reg++) {
        int rloc = wm * 64 + mi * 16 + quad * 4 + reg;
        long row = rowbase + rloc;
        const float* tg = Ttab + (long)go_off[row] * 1024;
        const float* tt = Ttab + (long)361 * 1024 + (long)to_off[row] * 1024;
#pragma unroll
        for (int ni = 0; ni < 4; ni++) {
          int cloc = wn * 64 + ni * 16 + r16;
          int col = colbase + cloc;
          float v = acc[mi][ni][reg] + tg[col] + tt[col] + bias[col];
          Cs[rloc * 136 + cloc] = f2bf(fmaxf(v, 0.f));
        }
      }
    }
    __syncthreads();
    // 128 rows x 16 chunks(16B) = 2048 chunks; 8 per thread, coalesced.
#pragma unroll
    for (int i = 0; i < 8; i++) {
      int c = i * 256 + tid;
      int r = c >> 4;
      int cc = c & 15;
      *(i32x4*)(h1out + (rowbase + r) * 1024 + colbase + cc * 8) =
          *(const i32x4*)&Cs[r * 136 + cc * 8];
    }
  } else {
#pragma unroll
    for (int mi = 0; mi < 4; mi++) {
#pragma unroll
      for (int reg = 0; reg < 4; reg++) {
        long row = rowbase + wm * 64 + mi * 16 + quad * 4 + reg;
        float part = 0.f;
#pragma unroll
        for (int ni = 0; ni < 4; ni++) {
          int col = colbase + wn * 64 + ni * 16 + r16;
          float v = fmaxf(acc[mi][ni][reg] + bias[col], 0.f);
          part += v * w3[col];
        }
        part += __shfl_xor(part, 1, 16);
        part += __shfl_xor(part, 2, 16);
        part += __shfl_xor(part, 4, 16);
        part += __shfl_xor(part, 8, 16);
        if (r16 == 0) atomicAdd(&scores[row], part);
      }
    }
  }
}

// ---------------------------------------------------------------- launch

extern "C" void kernel_launch(void* const* d_in, const int* in_sizes, int n_in,
                              void* d_out, int out_size, void* d_ws, size_t ws_size,
                              hipStream_t stream) {
  const float* pfm  = (const float*)d_in[0];  // (256,19,19)
  const float* cand = (const float*)d_in[1];  // (65536,64)
  const float* W1   = (const float*)d_in[2];  // (832,1024)
  const float* b1   = (const float*)d_in[3];  // (1024,)
  const float* W2   = (const float*)d_in[4];  // (1024,1024)
  const float* b2   = (const float*)d_in[5];  // (1024,)
  const float* W3   = (const float*)d_in[6];  // (1024,1)
  const float* b3   = (const float*)d_in[7];  // (1,)
  float* scores = (float*)d_out;              // (65536,)

  char* ws = (char*)d_ws;
  float*          gp      = (float*)(ws + 0);          //   1 KB
  float*          b1p     = (float*)(ws + 1024);       //   4 KB
  float*          Ttab    = (float*)(ws + 8192);       // 2*361*1024*4 = 2.83 MB
  int*            go_off  = (int*)(ws + 2965504);      // 256 KB
  int*            to_off  = (int*)(ws + 3227648);      // 256 KB
  unsigned short* cand_bf = (unsigned short*)(ws + 3489792);   // 8 MB
  unsigned short* w1cT    = (unsigned short*)(ws + 11878400);  // 128 KB
  unsigned short* w2T     = (unsigned short*)(ws + 12009472);  // 2 MB
  unsigned short* h1      = (unsigned short*)(ws + 14106624);  // 128 MB
  // total ws need: 148,324,352 bytes
  if (ws_size < 148324352) return;  // loud correctness failure instead of corruption

  pool_kernel<<<256, 64, 0, stream>>>(pfm, gp);
  b1p_kernel<<<4, 256, 0, stream>>>(W1, b1, gp, b1p);
  ttab_kernel<<<728, 256, 0, stream>>>(pfm, W1, Ttab);
  decode_kernel<<<256, 256, 0, stream>>>(cand, go_off, to_off);
  cvt_bf16_kernel<<<16384, 256, 0, stream>>>(cand, cand_bf);   // 65536*64
  w1ct_kernel<<<256, 256, 0, stream>>>(W1, w1cT);
  w2t_kernel<<<4096, 256, 0, stream>>>(W2, w2T);
  init_scores_kernel<<<256, 256, 0, stream>>>(scores, b3);

  // h1 = relu(cand@W1c + T_go[g] + T_to[t] + b1')   M=65536,K=64
  gemm_bt<0><<<4096, 256, 0, stream>>>(cand_bf, w1cT, 64, h1, Ttab, go_off, to_off,
                                       b1p, nullptr, nullptr);
  // scores += relu(h1@W2 + b2) @ w3                 M=65536,K=1024
  gemm_bt<1><<<4096, 256, 0, stream>>>(h1, w2T, 1024, nullptr, nullptr, nullptr,
                                       nullptr, b2, W3, scores);
}